// Round 5
// baseline (299.473 us; speedup 1.0000x reference)
//
#include <hip/hip_runtime.h>
#include <hip/hip_fp16.h>
#include <math.h>

// ---------------------------------------------------------------------------
// GCN 2-layer + two heads, fp32 in/out, MI355X.
//   CSR build (XCD-affine windowed histogram+fill: kills the 64B/edge write
//   amplification seen in round-4 counters: WRITE_SIZE 51.7MB ~= E*64B) ->
//   GEMMs via split-bf16 MFMA -> CSR gather aggregate over fp16 features.
// ---------------------------------------------------------------------------

#define DFEAT 128
#define NWIN 8
#define WSHIFT 13   // window = dst >> 13 (8192 nodes/window, 7 windows for N=50k)

using short8  = __attribute__((ext_vector_type(8))) short;
using floatx4 = __attribute__((ext_vector_type(4))) float;

__device__ __forceinline__ unsigned short f2bf_rne(float x) {
    unsigned u = __float_as_uint(x);
    unsigned r = u + 0x7FFFu + ((u >> 16) & 1u);
    return (unsigned short)(r >> 16);
}

// ---------------------------- CSR build (windowed) --------------------------
// Blocks of the same (blockIdx & 7) land on the same XCD (round-robin
// dispatch heuristic) -> each window's deg/cursor/col_idx slab stays in ONE
// L2 and writes back full lines. Reads are 8x re-streamed but L3-resident.

__global__ __launch_bounds__(256) void count_deg_win_k(const int* __restrict__ dst,
                                                       int* __restrict__ deg,
                                                       int E, int N) {
    int w = blockIdx.x & (NWIN - 1);
    if ((w << WSHIFT) >= N) return;            // empty window
    int c = blockIdx.x >> 3;
    int nchunk = gridDim.x >> 3;
    int len = ((E + nchunk - 1) / nchunk + 3) & ~3;
    int e0 = c * len;
    int e1 = E < e0 + len ? E : e0 + len;
    int e1a = e0 + ((e1 - e0 > 0 ? e1 - e0 : 0) & ~3);
    for (int e = e0 + (int)threadIdx.x * 4; e < e1a; e += 1024) {
        int4 d4 = *(const int4*)(dst + e);
        if ((d4.x >> WSHIFT) == w) atomicAdd(&deg[d4.x], 1);
        if ((d4.y >> WSHIFT) == w) atomicAdd(&deg[d4.y], 1);
        if ((d4.z >> WSHIFT) == w) atomicAdd(&deg[d4.z], 1);
        if ((d4.w >> WSHIFT) == w) atomicAdd(&deg[d4.w], 1);
    }
    for (int e = e1a + (int)threadIdx.x; e < e1; e += 256) {
        int d = dst[e];
        if ((d >> WSHIFT) == w) atomicAdd(&deg[d], 1);
    }
}

__global__ __launch_bounds__(256) void fill_csr_win_k(const int* __restrict__ src,
                                                      const int* __restrict__ dst,
                                                      int* __restrict__ cursor,
                                                      int* __restrict__ col_idx,
                                                      int E, int N) {
    int w = blockIdx.x & (NWIN - 1);
    if ((w << WSHIFT) >= N) return;
    int c = blockIdx.x >> 3;
    int nchunk = gridDim.x >> 3;
    int len = ((E + nchunk - 1) / nchunk + 3) & ~3;
    int e0 = c * len;
    int e1 = E < e0 + len ? E : e0 + len;
    int e1a = e0 + ((e1 - e0 > 0 ? e1 - e0 : 0) & ~3);
    for (int e = e0 + (int)threadIdx.x * 4; e < e1a; e += 1024) {
        int4 d4 = *(const int4*)(dst + e);
        int4 s4 = *(const int4*)(src + e);
        if ((d4.x >> WSHIFT) == w) { int p = atomicAdd(&cursor[d4.x], 1); col_idx[p] = s4.x; }
        if ((d4.y >> WSHIFT) == w) { int p = atomicAdd(&cursor[d4.y], 1); col_idx[p] = s4.y; }
        if ((d4.z >> WSHIFT) == w) { int p = atomicAdd(&cursor[d4.z], 1); col_idx[p] = s4.z; }
        if ((d4.w >> WSHIFT) == w) { int p = atomicAdd(&cursor[d4.w], 1); col_idx[p] = s4.w; }
    }
    for (int e = e1a + (int)threadIdx.x; e < e1; e += 256) {
        int d = dst[e];
        if ((d >> WSHIFT) == w) { int p = atomicAdd(&cursor[d], 1); col_idx[p] = src[e]; }
    }
}

__global__ __launch_bounds__(256) void scan_local_k(const int* __restrict__ deg,
                                                    int* __restrict__ row_ptr,
                                                    int* __restrict__ chunk_sums,
                                                    int n) {
    int wave = blockIdx.x * 4 + (threadIdx.x >> 6);
    int lane = threadIdx.x & 63;
    int nchunks = (n + 63) >> 6;
    if (wave >= nchunks) return;
    int i = wave * 64 + lane;
    int v = (i < n) ? deg[i] : 0;
    int x = v;
#pragma unroll
    for (int off = 1; off < 64; off <<= 1) {
        int y = __shfl_up(x, off);
        if (lane >= off) x += y;
    }
    if (i < n) row_ptr[i] = x - v;
    if (lane == 63) chunk_sums[wave] = x;
}

__global__ __launch_bounds__(1024) void scan_chunks_k(int* __restrict__ a, int nchunks) {
    __shared__ int s[1024];
    int tid = threadIdx.x;
    int v = (tid < nchunks) ? a[tid] : 0;
    s[tid] = v;
    __syncthreads();
    int x = v;
    for (int off = 1; off < 1024; off <<= 1) {
        int y = (tid >= off) ? s[tid - off] : 0;
        __syncthreads();
        x += y;
        s[tid] = x;
        __syncthreads();
    }
    if (tid < nchunks) a[tid] = x - v;
}

__global__ __launch_bounds__(256) void finalize_csr_k(int* __restrict__ row_ptr,
                                                      const int* __restrict__ chunk_offs,
                                                      int* __restrict__ cursor,
                                                      const int* __restrict__ deg,
                                                      float* __restrict__ dinv,
                                                      int n, int E) {
    int i = blockIdx.x * 256 + threadIdx.x;
    if (i < n) {
        int rp = row_ptr[i] + chunk_offs[i >> 6];
        row_ptr[i] = rp;
        cursor[i] = rp;
        dinv[i] = rsqrtf((float)(deg[i] + 1));   // +1 self loop
    }
    if (i == 0) row_ptr[n] = E;
}

// ------------------------- W pre-split to MFMA frags ------------------------
__global__ __launch_bounds__(256) void prep_w4_k(const float* __restrict__ W0,
                                                 const float* __restrict__ W1,
                                                 const float* __restrict__ W2,
                                                 const float* __restrict__ W3,
                                                 short* __restrict__ hi_all,
                                                 short* __restrict__ lo_all) {
    int b = blockIdx.x >> 6;
    const float* W = (b == 0) ? W0 : (b == 1) ? W1 : (b == 2) ? W2 : W3;
    short* hi = hi_all + (size_t)b * 16384;
    short* lo = lo_all + (size_t)b * 16384;
    int i = (blockIdx.x & 63) * 256 + threadIdx.x;
    int j = i & 7;
    int lane = (i >> 3) & 63;
    int ts = i >> 9;
    int s = ts & 3, t = ts >> 2;
    int k = s * 32 + (lane >> 4) * 8 + j;
    int n = t * 16 + (lane & 15);
    float x = W[k * 128 + n];
    unsigned short h = f2bf_rne(x);
    float res = x - __uint_as_float(((unsigned)h) << 16);
    hi[i] = (short)h;
    lo[i] = (short)f2bf_rne(res);
}

// ----------------------- GEMM via split-bf16 MFMA ---------------------------
template <typename InT, typename OutT, bool SCALE, bool BIAS, bool RELU>
__device__ __forceinline__ void gemm_core(const InT* __restrict__ X,
                                          const short* __restrict__ Whi,
                                          const short* __restrict__ Wlo,
                                          const float* __restrict__ scale,
                                          const float* __restrict__ bias,
                                          OutT* __restrict__ Y, int M, int blk) {
    __shared__ short WhiS[16384];
    __shared__ short WloS[16384];
    const int tid = threadIdx.x;

#pragma unroll
    for (int j = 0; j < 8; ++j)
        ((float4*)WhiS)[tid + j * 256] = ((const float4*)Whi)[tid + j * 256];
#pragma unroll
    for (int j = 0; j < 8; ++j)
        ((float4*)WloS)[tid + j * 256] = ((const float4*)Wlo)[tid + j * 256];

    const int wave = tid >> 6, lane = tid & 63;
    const int quad = lane >> 4, l16 = lane & 15;
    const int m0 = blk * 128 + wave * 32;

    short8 Ahi[2][4], Alo[2][4];
#pragma unroll
    for (int r = 0; r < 2; ++r) {
        int row = m0 + r * 16 + l16;
        row = row < M ? row : (M - 1);
        const InT* xr = X + (size_t)row * 128 + quad * 8;
#pragma unroll
        for (int s = 0; s < 4; ++s) {
            float v[8];
            if constexpr (sizeof(InT) == 4) {
                float4 a = ((const float4*)(xr + s * 32))[0];
                float4 b = ((const float4*)(xr + s * 32))[1];
                v[0] = a.x; v[1] = a.y; v[2] = a.z; v[3] = a.w;
                v[4] = b.x; v[5] = b.y; v[6] = b.z; v[7] = b.w;
            } else {
                uint4 raw = *(const uint4*)(xr + s * 32);
                const __half2* hp = (const __half2*)&raw;
#pragma unroll
                for (int k = 0; k < 4; ++k) {
                    float2 f = __half22float2(hp[k]);
                    v[2 * k] = f.x; v[2 * k + 1] = f.y;
                }
            }
#pragma unroll
            for (int j = 0; j < 8; ++j) {
                unsigned short h = f2bf_rne(v[j]);
                Ahi[r][s][j] = (short)h;
                float res = v[j] - __uint_as_float(((unsigned)h) << 16);
                Alo[r][s][j] = (short)f2bf_rne(res);
            }
        }
    }

    __syncthreads();

    floatx4 acc[2][8];
#pragma unroll
    for (int r = 0; r < 2; ++r)
#pragma unroll
        for (int t = 0; t < 8; ++t) acc[r][t] = (floatx4){0.f, 0.f, 0.f, 0.f};

    const short8* WH = (const short8*)WhiS;
    const short8* WL = (const short8*)WloS;
#pragma unroll
    for (int s = 0; s < 4; ++s) {
#pragma unroll
        for (int t = 0; t < 8; ++t) {
            short8 bh = WH[(t * 4 + s) * 64 + lane];
            short8 bl = WL[(t * 4 + s) * 64 + lane];
#pragma unroll
            for (int r = 0; r < 2; ++r) {
                acc[r][t] = __builtin_amdgcn_mfma_f32_16x16x32_bf16(Ahi[r][s], bh, acc[r][t], 0, 0, 0);
                acc[r][t] = __builtin_amdgcn_mfma_f32_16x16x32_bf16(Alo[r][s], bh, acc[r][t], 0, 0, 0);
                acc[r][t] = __builtin_amdgcn_mfma_f32_16x16x32_bf16(Ahi[r][s], bl, acc[r][t], 0, 0, 0);
            }
        }
    }

    float bcol[8];
    if (BIAS) {
#pragma unroll
        for (int t = 0; t < 8; ++t) bcol[t] = bias[t * 16 + l16];
    }
#pragma unroll
    for (int r = 0; r < 2; ++r) {
#pragma unroll
        for (int e = 0; e < 4; ++e) {
            int row = m0 + r * 16 + quad * 4 + e;
            if (row < M) {
                float sc = SCALE ? scale[row] : 1.f;
                OutT* yr = Y + (size_t)row * 128 + l16;
#pragma unroll
                for (int t = 0; t < 8; ++t) {
                    float v = acc[r][t][e];
                    if (SCALE) v *= sc;
                    if (BIAS) v += bcol[t];
                    if (RELU) v = fmaxf(v, 0.f);
                    if constexpr (sizeof(OutT) == 4) yr[t * 16] = v;
                    else yr[t * 16] = __float2half(v);
                }
            }
        }
    }
}

template <typename InT, typename OutT, bool SCALE, bool BIAS, bool RELU>
__global__ __launch_bounds__(256) void gemm_k(const InT* __restrict__ X,
                                              const short* __restrict__ Whi,
                                              const short* __restrict__ Wlo,
                                              const float* __restrict__ scale,
                                              const float* __restrict__ bias,
                                              OutT* __restrict__ Y, int M) {
    gemm_core<InT, OutT, SCALE, BIAS, RELU>(X, Whi, Wlo, scale, bias, Y, M, blockIdx.x);
}

__global__ __launch_bounds__(256) void gemm_heads_k(const float* __restrict__ X,
                                                    const short* __restrict__ WhiV,
                                                    const short* __restrict__ WloV,
                                                    const short* __restrict__ WhiT,
                                                    const short* __restrict__ WloT,
                                                    const float* __restrict__ bv,
                                                    const float* __restrict__ bt,
                                                    float* __restrict__ Yv,
                                                    float* __restrict__ Yt,
                                                    int M, int gb) {
    bool second = blockIdx.x >= gb;
    const short* hi = second ? WhiT : WhiV;
    const short* lo = second ? WloT : WloV;
    const float* b  = second ? bt : bv;
    float* Y        = second ? Yt : Yv;
    int blk         = second ? (blockIdx.x - gb) : blockIdx.x;
    gemm_core<float, float, false, true, true>(X, hi, lo, nullptr, b, Y, M, blk);
}

// ----------------------------- Aggregate ------------------------------------
template <bool RELU, typename OutT>
__global__ __launch_bounds__(256) void agg_k(const __half* __restrict__ hs,
                                             const int* __restrict__ row_ptr,
                                             const int* __restrict__ col_idx,
                                             const float* __restrict__ dinv,
                                             const float* __restrict__ bias,
                                             OutT* __restrict__ out, int n) {
    int wv = blockIdx.x * 4 + (threadIdx.x >> 6);
    int lane = threadIdx.x & 63;
    int g = lane >> 4, c = lane & 15;
    int nw = gridDim.x * 4;

    for (int i = wv; i < n; i += nw) {
        float acc[8];
        if (g == 0) {
            uint4 raw = ((const uint4*)(hs + (size_t)i * DFEAT))[c];
            const __half2* hp = (const __half2*)&raw;
#pragma unroll
            for (int k = 0; k < 4; ++k) {
                float2 f = __half22float2(hp[k]);
                acc[2 * k] = f.x; acc[2 * k + 1] = f.y;
            }
        } else {
#pragma unroll
            for (int k = 0; k < 8; ++k) acc[k] = 0.f;
        }

        int s = row_ptr[i];
        int cnt = row_ptr[i + 1] - s;

        for (int base = 0; base < cnt; base += 64) {
            int t = base + lane;
            int idx = (t < cnt) ? col_idx[s + t] : 0;
            int lim = cnt - base; if (lim > 64) lim = 64;
            for (int j = 0; j < lim; j += 16) {
                int sl0 = j + g, sl1 = j + 4 + g, sl2 = j + 8 + g, sl3 = j + 12 + g;
                int i0 = __shfl(idx, sl0), i1 = __shfl(idx, sl1);
                int i2 = __shfl(idx, sl2), i3 = __shfl(idx, sl3);
                float m0 = sl0 < lim ? 1.f : 0.f;
                float m1 = sl1 < lim ? 1.f : 0.f;
                float m2 = sl2 < lim ? 1.f : 0.f;
                float m3 = sl3 < lim ? 1.f : 0.f;
                uint4 v0 = ((const uint4*)(hs + (size_t)(sl0 < lim ? i0 : i) * DFEAT))[c];
                uint4 v1 = ((const uint4*)(hs + (size_t)(sl1 < lim ? i1 : i) * DFEAT))[c];
                uint4 v2 = ((const uint4*)(hs + (size_t)(sl2 < lim ? i2 : i) * DFEAT))[c];
                uint4 v3 = ((const uint4*)(hs + (size_t)(sl3 < lim ? i3 : i) * DFEAT))[c];
                const __half2* p0 = (const __half2*)&v0;
                const __half2* p1 = (const __half2*)&v1;
                const __half2* p2 = (const __half2*)&v2;
                const __half2* p3 = (const __half2*)&v3;
#pragma unroll
                for (int k = 0; k < 4; ++k) {
                    float2 f0 = __half22float2(p0[k]);
                    float2 f1 = __half22float2(p1[k]);
                    float2 f2 = __half22float2(p2[k]);
                    float2 f3 = __half22float2(p3[k]);
                    acc[2 * k]     = fmaf(f0.x, m0, acc[2 * k]);
                    acc[2 * k + 1] = fmaf(f0.y, m0, acc[2 * k + 1]);
                    acc[2 * k]     = fmaf(f1.x, m1, acc[2 * k]);
                    acc[2 * k + 1] = fmaf(f1.y, m1, acc[2 * k + 1]);
                    acc[2 * k]     = fmaf(f2.x, m2, acc[2 * k]);
                    acc[2 * k + 1] = fmaf(f2.y, m2, acc[2 * k + 1]);
                    acc[2 * k]     = fmaf(f3.x, m3, acc[2 * k]);
                    acc[2 * k + 1] = fmaf(f3.y, m3, acc[2 * k + 1]);
                }
            }
        }

#pragma unroll
        for (int k = 0; k < 8; ++k) {
            acc[k] += __shfl_xor(acc[k], 16);
            acc[k] += __shfl_xor(acc[k], 32);
        }

        if (g == 0) {
            float di = dinv[i];
            float4 b0 = ((const float4*)bias)[c * 2];
            float4 b1 = ((const float4*)bias)[c * 2 + 1];
            float o[8];
            o[0] = fmaf(acc[0], di, b0.x); o[1] = fmaf(acc[1], di, b0.y);
            o[2] = fmaf(acc[2], di, b0.z); o[3] = fmaf(acc[3], di, b0.w);
            o[4] = fmaf(acc[4], di, b1.x); o[5] = fmaf(acc[5], di, b1.y);
            o[6] = fmaf(acc[6], di, b1.z); o[7] = fmaf(acc[7], di, b1.w);
            if (RELU) {
#pragma unroll
                for (int k = 0; k < 8; ++k) o[k] = fmaxf(o[k], 0.f);
            }
            if constexpr (sizeof(OutT) == 4) {
                float4 w0 = make_float4(o[0], o[1], o[2], o[3]);
                float4 w1 = make_float4(o[4], o[5], o[6], o[7]);
                ((float4*)((float*)out + (size_t)i * DFEAT))[c * 2] = w0;
                ((float4*)((float*)out + (size_t)i * DFEAT))[c * 2 + 1] = w1;
            } else {
                __half2 hpk[4];
#pragma unroll
                for (int k = 0; k < 4; ++k)
                    hpk[k] = __floats2half2_rn(o[2 * k], o[2 * k + 1]);
                ((uint4*)((__half*)out + (size_t)i * DFEAT))[c] = *(uint4*)hpk;
            }
        }
    }
}

// ---------------------------------------------------------------------------

static inline size_t align_up(size_t x, size_t a) { return (x + a - 1) & ~(a - 1); }

extern "C" void kernel_launch(void* const* d_in, const int* in_sizes, int n_in,
                              void* d_out, int out_size, void* d_ws, size_t ws_size,
                              hipStream_t stream) {
    const float* x  = (const float*)d_in[0];
    const int*   ei = (const int*)d_in[1];
    const float* W0 = (const float*)d_in[2];
    const float* b0 = (const float*)d_in[3];
    const float* W1 = (const float*)d_in[4];
    const float* b1 = (const float*)d_in[5];
    const float* Wv = (const float*)d_in[6];
    const float* bv = (const float*)d_in[7];
    const float* Wt = (const float*)d_in[8];
    const float* bt = (const float*)d_in[9];

    const int N = in_sizes[0] / DFEAT;
    const int E = in_sizes[1] / 2;
    const int* src = ei;
    const int* dst = ei + E;

    const int nchunks = (N + 63) >> 6;

    // workspace carve-up
    char* w = (char*)d_ws;
    int* deg        = (int*)w;  w += align_up((size_t)N * 4, 256);
    int* row_ptr    = (int*)w;  w += align_up((size_t)(N + 1) * 4, 256);
    int* cursor     = (int*)w;  w += align_up((size_t)N * 4, 256);
    int* chunk_sums = (int*)w;  w += align_up((size_t)(nchunks + 1) * 4, 256);
    int* col_idx    = (int*)w;  w += align_up((size_t)E * 4, 256);
    float* dinv     = (float*)w; w += align_up((size_t)N * 4, 256);
    short* whi_all  = (short*)w; w += align_up(4 * 16384 * 2, 256);
    short* wlo_all  = (short*)w; w += align_up(4 * 16384 * 2, 256);
    __half* hs      = (__half*)w; w += align_up((size_t)N * DFEAT * 2, 256);
    __half* h1      = (__half*)w; w += align_up((size_t)N * DFEAT * 2, 256);

    short* w0hi = whi_all;            short* w0lo = wlo_all;
    short* w1hi = whi_all + 16384;    short* w1lo = wlo_all + 16384;
    short* wvhi = whi_all + 2*16384;  short* wvlo = wlo_all + 2*16384;
    short* wthi = whi_all + 3*16384;  short* wtlo = wlo_all + 3*16384;

    float* out_h = (float*)d_out;
    float* out_v = out_h + (size_t)N * DFEAT;
    float* out_t = out_h + 2 * (size_t)N * DFEAT;

    const int nb = (N + 255) / 256;
    const int gb = (N + 127) / 128;
    const int agg_blocks = 2048;
    const int win_blocks = NWIN * 64;   // 8 windows x 64 chunks

    // CSR build + weight pre-split
    hipMemsetAsync(deg, 0, (size_t)N * 4, stream);
    count_deg_win_k<<<win_blocks, 256, 0, stream>>>(dst, deg, E, N);
    prep_w4_k<<<256, 256, 0, stream>>>(W0, W1, Wv, Wt, whi_all, wlo_all);
    scan_local_k<<<(nchunks + 3) / 4, 256, 0, stream>>>(deg, row_ptr, chunk_sums, N);
    scan_chunks_k<<<1, 1024, 0, stream>>>(chunk_sums, nchunks);
    finalize_csr_k<<<nb, 256, 0, stream>>>(row_ptr, chunk_sums, cursor, deg, dinv, N, E);
    fill_csr_win_k<<<win_blocks, 256, 0, stream>>>(src, dst, cursor, col_idx, E, N);

    // layer 0: hs = fp16( dinv * (x @ W0) )
    gemm_k<float, __half, true, false, false><<<gb, 256, 0, stream>>>(x, w0hi, w0lo, dinv, nullptr, hs, N);
    // h1 = fp16( relu(dinv * agg(hs) + b0) )
    agg_k<true, __half><<<agg_blocks, 256, 0, stream>>>(hs, row_ptr, col_idx, dinv, b0, h1, N);
    // layer 1: hs = fp16( dinv * (h1 @ W1) )
    gemm_k<__half, __half, true, false, false><<<gb, 256, 0, stream>>>(h1, w1hi, w1lo, dinv, nullptr, hs, N);
    // h = dinv * agg(hs) + b1 -> d_out (fp32)
    agg_k<false, float><<<agg_blocks, 256, 0, stream>>>(hs, row_ptr, col_idx, dinv, b1, out_h, N);
    // heads (fused dispatch)
    gemm_heads_k<<<2 * gb, 256, 0, stream>>>(out_h, wvhi, wvlo, wthi, wtlo, bv, bt, out_v, out_t, N, gb);
}

// Round 6
// 267.351 us; speedup vs baseline: 1.1201x; 1.1201x over previous
//
#include <hip/hip_runtime.h>
#include <hip/hip_fp16.h>
#include <math.h>

// ---------------------------------------------------------------------------
// GCN 2-layer + two heads, fp32 in/out, MI355X.
//   CSR build via 2-level counting sort (atomic-light: round-5 showed the
//   ~96us CSR cost is device-scope random-atomic throughput, ~18G atomics/s,
//   NOT write amplification -> eliminate per-edge global atomics) ->
//   GEMMs via split-bf16 MFMA -> CSR gather aggregate over fp16 features.
// ---------------------------------------------------------------------------

#define DFEAT 128
#define BSH 8            // bucket = dst >> 8 (256 nodes/bucket)
#define BKE 4096         // edges per partition block

using short8  = __attribute__((ext_vector_type(8))) short;
using floatx4 = __attribute__((ext_vector_type(4))) float;

__device__ __forceinline__ unsigned short f2bf_rne(float x) {
    unsigned u = __float_as_uint(x);
    unsigned r = u + 0x7FFFu + ((u >> 16) & 1u);
    return (unsigned short)(r >> 16);
}

// ------------------- Pass A: coarse bucket histogram ------------------------
__global__ __launch_bounds__(256) void bucket_hist_k(const int* __restrict__ dst,
                                                     int* __restrict__ bucket_cnt,
                                                     int E, int nbuk) {
    __shared__ int h[256];
    int tid = threadIdx.x;
    h[tid] = 0;
    __syncthreads();
    int nb = gridDim.x;
    int len = ((E + nb - 1) / nb + 3) & ~3;
    int e0 = blockIdx.x * len;
    int e1 = E < e0 + len ? E : e0 + len;
    int m = e1 - e0; if (m < 0) m = 0;
    int e1a = e0 + (m & ~3);
    for (int e = e0 + tid * 4; e < e1a; e += 1024) {
        int4 d4 = *(const int4*)(dst + e);
        atomicAdd(&h[d4.x >> BSH], 1);
        atomicAdd(&h[d4.y >> BSH], 1);
        atomicAdd(&h[d4.z >> BSH], 1);
        atomicAdd(&h[d4.w >> BSH], 1);
    }
    for (int e = e1a + tid; e < e1; e += 256) atomicAdd(&h[dst[e] >> BSH], 1);
    __syncthreads();
    if (tid < nbuk && h[tid]) atomicAdd(&bucket_cnt[tid], h[tid]);
}

// ------------------- scan bucket counts -> offsets + cursor ----------------
__global__ __launch_bounds__(256) void scan_buckets_k(const int* __restrict__ cnt,
                                                      int* __restrict__ off,
                                                      int* __restrict__ cursor,
                                                      int nbuk, int E) {
    __shared__ int s[256];
    int tid = threadIdx.x;
    int v = (tid < nbuk) ? cnt[tid] : 0;
    s[tid] = v;
    __syncthreads();
    int x = v;
    for (int o = 1; o < 256; o <<= 1) {
        int y = (tid >= o) ? s[tid - o] : 0;
        __syncthreads();
        x += y;
        s[tid] = x;
        __syncthreads();
    }
    if (tid < nbuk) { off[tid] = x - v; cursor[tid] = x - v; }
    if (tid == 0) off[nbuk] = E;
}

// ------------------- Pass B: partition edges into buckets -------------------
// 196 blocks x 4096 edges. LDS rank atomics + one global reservation atomic
// per (block,bucket). Writes packed (dst<<16 | src) in ~21-entry runs.
__global__ __launch_bounds__(256) void partition_k(const int* __restrict__ src,
                                                   const int* __restrict__ dst,
                                                   int* __restrict__ cursor,
                                                   unsigned* __restrict__ pk_out,
                                                   int E, int nbuk) {
    __shared__ int h[256];
    __shared__ int base[256];
    int tid = threadIdx.x;
    h[tid] = 0;
    __syncthreads();
    int e0 = blockIdx.x * BKE;

    unsigned pk[16];
    unsigned short rk[16];
    unsigned char bk[16];
    int m = 0;
#pragma unroll
    for (int it = 0; it < 4; ++it) {
        int e = e0 + it * 1024 + tid * 4;
        if (e + 3 < E) {
            int4 d4 = *(const int4*)(dst + e);
            int4 s4 = *(const int4*)(src + e);
            int dd[4] = {d4.x, d4.y, d4.z, d4.w};
            int ss[4] = {s4.x, s4.y, s4.z, s4.w};
#pragma unroll
            for (int k = 0; k < 4; ++k) {
                int b = dd[k] >> BSH;
                pk[m] = ((unsigned)dd[k] << 16) | (unsigned)ss[k];
                rk[m] = (unsigned short)atomicAdd(&h[b], 1);
                bk[m] = (unsigned char)b;
                ++m;
            }
        } else {
            for (int k = 0; k < 4; ++k) {
                if (e + k < E) {
                    int d = dst[e + k], sv = src[e + k];
                    int b = d >> BSH;
                    pk[m] = ((unsigned)d << 16) | (unsigned)sv;
                    rk[m] = (unsigned short)atomicAdd(&h[b], 1);
                    bk[m] = (unsigned char)b;
                    ++m;
                }
            }
        }
    }
    __syncthreads();
    if (tid < nbuk && h[tid]) base[tid] = atomicAdd(&cursor[tid], h[tid]);
    __syncthreads();
    for (int j = 0; j < m; ++j)
        pk_out[base[bk[j]] + (int)rk[j]] = pk[j];
}

// ------------------- Pass C: per-bucket exact CSR ---------------------------
// One block per bucket. LDS histogram of 256 local nodes + LDS scan ->
// row_ptr, dinv, and col_idx (ushort) into a block-exclusive slab.
__global__ __launch_bounds__(256) void build_csr_k(const unsigned* __restrict__ pk_arr,
                                                   const int* __restrict__ off,
                                                   int* __restrict__ row_ptr,
                                                   unsigned short* __restrict__ col_idx,
                                                   float* __restrict__ dinv,
                                                   int N, int E) {
    __shared__ int hcnt[256];
    __shared__ int esc[256];
    int b = blockIdx.x, tid = threadIdx.x;
    hcnt[tid] = 0;
    __syncthreads();
    int s0 = off[b], s1 = off[b + 1];
    int cnt = s1 - s0;

    unsigned p[20];
    unsigned short r[20];
    int m = 0;
    for (int i = tid; i < cnt; i += 256) {
        unsigned pp = pk_arr[s0 + i];
        int d = (pp >> 16) & 255;
        r[m] = (unsigned short)atomicAdd(&hcnt[d], 1);
        p[m] = pp;
        ++m;
    }
    __syncthreads();

    int v = hcnt[tid];
    esc[tid] = v;
    __syncthreads();
    int x = v;
    for (int o = 1; o < 256; o <<= 1) {
        int y = (tid >= o) ? esc[tid - o] : 0;
        __syncthreads();
        x += y;
        esc[tid] = x;
        __syncthreads();
    }
    int excl = x - v;
    __syncthreads();
    esc[tid] = excl;
    __syncthreads();

    int node = (b << BSH) + tid;
    if (node < N) {
        row_ptr[node] = s0 + excl;
        dinv[node] = rsqrtf((float)(v + 1));   // +1 self loop
    }
    if (node == N) row_ptr[N] = E;

    for (int j = 0; j < m; ++j) {
        int d = (p[j] >> 16) & 255;
        col_idx[s0 + esc[d] + (int)r[j]] = (unsigned short)(p[j] & 0xFFFFu);
    }
}

// ------------------------- W pre-split to MFMA frags ------------------------
__global__ __launch_bounds__(256) void prep_w4_k(const float* __restrict__ W0,
                                                 const float* __restrict__ W1,
                                                 const float* __restrict__ W2,
                                                 const float* __restrict__ W3,
                                                 short* __restrict__ hi_all,
                                                 short* __restrict__ lo_all) {
    int b = blockIdx.x >> 6;
    const float* W = (b == 0) ? W0 : (b == 1) ? W1 : (b == 2) ? W2 : W3;
    short* hi = hi_all + (size_t)b * 16384;
    short* lo = lo_all + (size_t)b * 16384;
    int i = (blockIdx.x & 63) * 256 + threadIdx.x;
    int j = i & 7;
    int lane = (i >> 3) & 63;
    int ts = i >> 9;
    int s = ts & 3, t = ts >> 2;
    int k = s * 32 + (lane >> 4) * 8 + j;
    int n = t * 16 + (lane & 15);
    float x = W[k * 128 + n];
    unsigned short h = f2bf_rne(x);
    float res = x - __uint_as_float(((unsigned)h) << 16);
    hi[i] = (short)h;
    lo[i] = (short)f2bf_rne(res);
}

// ----------------------- GEMM via split-bf16 MFMA ---------------------------
template <typename InT, typename OutT, bool SCALE, bool BIAS, bool RELU>
__device__ __forceinline__ void gemm_core(const InT* __restrict__ X,
                                          const short* __restrict__ Whi,
                                          const short* __restrict__ Wlo,
                                          const float* __restrict__ scale,
                                          const float* __restrict__ bias,
                                          OutT* __restrict__ Y, int M, int blk) {
    __shared__ short WhiS[16384];
    __shared__ short WloS[16384];
    const int tid = threadIdx.x;

#pragma unroll
    for (int j = 0; j < 8; ++j)
        ((float4*)WhiS)[tid + j * 256] = ((const float4*)Whi)[tid + j * 256];
#pragma unroll
    for (int j = 0; j < 8; ++j)
        ((float4*)WloS)[tid + j * 256] = ((const float4*)Wlo)[tid + j * 256];

    const int wave = tid >> 6, lane = tid & 63;
    const int quad = lane >> 4, l16 = lane & 15;
    const int m0 = blk * 128 + wave * 32;

    short8 Ahi[2][4], Alo[2][4];
#pragma unroll
    for (int r = 0; r < 2; ++r) {
        int row = m0 + r * 16 + l16;
        row = row < M ? row : (M - 1);
        const InT* xr = X + (size_t)row * 128 + quad * 8;
#pragma unroll
        for (int s = 0; s < 4; ++s) {
            float v[8];
            if constexpr (sizeof(InT) == 4) {
                float4 a = ((const float4*)(xr + s * 32))[0];
                float4 b = ((const float4*)(xr + s * 32))[1];
                v[0] = a.x; v[1] = a.y; v[2] = a.z; v[3] = a.w;
                v[4] = b.x; v[5] = b.y; v[6] = b.z; v[7] = b.w;
            } else {
                uint4 raw = *(const uint4*)(xr + s * 32);
                const __half2* hp = (const __half2*)&raw;
#pragma unroll
                for (int k = 0; k < 4; ++k) {
                    float2 f = __half22float2(hp[k]);
                    v[2 * k] = f.x; v[2 * k + 1] = f.y;
                }
            }
#pragma unroll
            for (int j = 0; j < 8; ++j) {
                unsigned short h = f2bf_rne(v[j]);
                Ahi[r][s][j] = (short)h;
                float res = v[j] - __uint_as_float(((unsigned)h) << 16);
                Alo[r][s][j] = (short)f2bf_rne(res);
            }
        }
    }

    __syncthreads();

    floatx4 acc[2][8];
#pragma unroll
    for (int r = 0; r < 2; ++r)
#pragma unroll
        for (int t = 0; t < 8; ++t) acc[r][t] = (floatx4){0.f, 0.f, 0.f, 0.f};

    const short8* WH = (const short8*)WhiS;
    const short8* WL = (const short8*)WloS;
#pragma unroll
    for (int s = 0; s < 4; ++s) {
#pragma unroll
        for (int t = 0; t < 8; ++t) {
            short8 bh = WH[(t * 4 + s) * 64 + lane];
            short8 bl = WL[(t * 4 + s) * 64 + lane];
#pragma unroll
            for (int r = 0; r < 2; ++r) {
                acc[r][t] = __builtin_amdgcn_mfma_f32_16x16x32_bf16(Ahi[r][s], bh, acc[r][t], 0, 0, 0);
                acc[r][t] = __builtin_amdgcn_mfma_f32_16x16x32_bf16(Alo[r][s], bh, acc[r][t], 0, 0, 0);
                acc[r][t] = __builtin_amdgcn_mfma_f32_16x16x32_bf16(Ahi[r][s], bl, acc[r][t], 0, 0, 0);
            }
        }
    }

    float bcol[8];
    if (BIAS) {
#pragma unroll
        for (int t = 0; t < 8; ++t) bcol[t] = bias[t * 16 + l16];
    }
#pragma unroll
    for (int r = 0; r < 2; ++r) {
#pragma unroll
        for (int e = 0; e < 4; ++e) {
            int row = m0 + r * 16 + quad * 4 + e;
            if (row < M) {
                float sc = SCALE ? scale[row] : 1.f;
                OutT* yr = Y + (size_t)row * 128 + l16;
#pragma unroll
                for (int t = 0; t < 8; ++t) {
                    float v = acc[r][t][e];
                    if (SCALE) v *= sc;
                    if (BIAS) v += bcol[t];
                    if (RELU) v = fmaxf(v, 0.f);
                    if constexpr (sizeof(OutT) == 4) yr[t * 16] = v;
                    else yr[t * 16] = __float2half(v);
                }
            }
        }
    }
}

template <typename InT, typename OutT, bool SCALE, bool BIAS, bool RELU>
__global__ __launch_bounds__(256) void gemm_k(const InT* __restrict__ X,
                                              const short* __restrict__ Whi,
                                              const short* __restrict__ Wlo,
                                              const float* __restrict__ scale,
                                              const float* __restrict__ bias,
                                              OutT* __restrict__ Y, int M) {
    gemm_core<InT, OutT, SCALE, BIAS, RELU>(X, Whi, Wlo, scale, bias, Y, M, blockIdx.x);
}

__global__ __launch_bounds__(256) void gemm_heads_k(const float* __restrict__ X,
                                                    const short* __restrict__ WhiV,
                                                    const short* __restrict__ WloV,
                                                    const short* __restrict__ WhiT,
                                                    const short* __restrict__ WloT,
                                                    const float* __restrict__ bv,
                                                    const float* __restrict__ bt,
                                                    float* __restrict__ Yv,
                                                    float* __restrict__ Yt,
                                                    int M, int gb) {
    bool second = blockIdx.x >= gb;
    const short* hi = second ? WhiT : WhiV;
    const short* lo = second ? WloT : WloV;
    const float* b  = second ? bt : bv;
    float* Y        = second ? Yt : Yv;
    int blk         = second ? (blockIdx.x - gb) : blockIdx.x;
    gemm_core<float, float, false, true, true>(X, hi, lo, nullptr, b, Y, M, blk);
}

// ----------------------------- Aggregate ------------------------------------
// out[i] = op( dinv[i]*(hs[i] + sum_nb hs[col]) + b ), hs fp16, col_idx ushort.
// One node/wave; 4 lane-groups x 8 unrolled gathers -> 8 uint4 in flight.
template <bool RELU, typename OutT>
__global__ __launch_bounds__(256) void agg_k(const __half* __restrict__ hs,
                                             const int* __restrict__ row_ptr,
                                             const unsigned short* __restrict__ col_idx,
                                             const float* __restrict__ dinv,
                                             const float* __restrict__ bias,
                                             OutT* __restrict__ out, int n) {
    int wv = blockIdx.x * 4 + (threadIdx.x >> 6);
    int lane = threadIdx.x & 63;
    int g = lane >> 4, c = lane & 15;
    int nw = gridDim.x * 4;

    for (int i = wv; i < n; i += nw) {
        float acc[8];
        if (g == 0) {
            uint4 raw = ((const uint4*)(hs + (size_t)i * DFEAT))[c];
            const __half2* hp = (const __half2*)&raw;
#pragma unroll
            for (int k = 0; k < 4; ++k) {
                float2 f = __half22float2(hp[k]);
                acc[2 * k] = f.x; acc[2 * k + 1] = f.y;
            }
        } else {
#pragma unroll
            for (int k = 0; k < 8; ++k) acc[k] = 0.f;
        }

        int s = row_ptr[i];
        int cnt = row_ptr[i + 1] - s;

        for (int base = 0; base < cnt; base += 64) {
            int t = base + lane;
            int idx = (t < cnt) ? (int)col_idx[s + t] : 0;
            int lim = cnt - base; if (lim > 64) lim = 64;
            for (int j = 0; j < lim; j += 32) {
                int sl[8], ia[8];
                float mk[8];
#pragma unroll
                for (int q = 0; q < 8; ++q) {
                    sl[q] = j + q * 4 + g;
                    ia[q] = __shfl(idx, sl[q]);
                    mk[q] = sl[q] < lim ? 1.f : 0.f;
                }
                uint4 vv[8];
#pragma unroll
                for (int q = 0; q < 8; ++q)
                    vv[q] = ((const uint4*)(hs + (size_t)(sl[q] < lim ? ia[q] : i) * DFEAT))[c];
#pragma unroll
                for (int q = 0; q < 8; ++q) {
                    const __half2* pq = (const __half2*)&vv[q];
#pragma unroll
                    for (int k = 0; k < 4; ++k) {
                        float2 f = __half22float2(pq[k]);
                        acc[2 * k]     = fmaf(f.x, mk[q], acc[2 * k]);
                        acc[2 * k + 1] = fmaf(f.y, mk[q], acc[2 * k + 1]);
                    }
                }
            }
        }

#pragma unroll
        for (int k = 0; k < 8; ++k) {
            acc[k] += __shfl_xor(acc[k], 16);
            acc[k] += __shfl_xor(acc[k], 32);
        }

        if (g == 0) {
            float di = dinv[i];
            float4 b0 = ((const float4*)bias)[c * 2];
            float4 b1 = ((const float4*)bias)[c * 2 + 1];
            float o[8];
            o[0] = fmaf(acc[0], di, b0.x); o[1] = fmaf(acc[1], di, b0.y);
            o[2] = fmaf(acc[2], di, b0.z); o[3] = fmaf(acc[3], di, b0.w);
            o[4] = fmaf(acc[4], di, b1.x); o[5] = fmaf(acc[5], di, b1.y);
            o[6] = fmaf(acc[6], di, b1.z); o[7] = fmaf(acc[7], di, b1.w);
            if (RELU) {
#pragma unroll
                for (int k = 0; k < 8; ++k) o[k] = fmaxf(o[k], 0.f);
            }
            if constexpr (sizeof(OutT) == 4) {
                float4 w0 = make_float4(o[0], o[1], o[2], o[3]);
                float4 w1 = make_float4(o[4], o[5], o[6], o[7]);
                ((float4*)((float*)out + (size_t)i * DFEAT))[c * 2] = w0;
                ((float4*)((float*)out + (size_t)i * DFEAT))[c * 2 + 1] = w1;
            } else {
                __half2 hpk[4];
#pragma unroll
                for (int k = 0; k < 4; ++k)
                    hpk[k] = __floats2half2_rn(o[2 * k], o[2 * k + 1]);
                ((uint4*)((__half*)out + (size_t)i * DFEAT))[c] = *(uint4*)hpk;
            }
        }
    }
}

// ---------------------------------------------------------------------------

static inline size_t align_up(size_t x, size_t a) { return (x + a - 1) & ~(a - 1); }

extern "C" void kernel_launch(void* const* d_in, const int* in_sizes, int n_in,
                              void* d_out, int out_size, void* d_ws, size_t ws_size,
                              hipStream_t stream) {
    const float* x  = (const float*)d_in[0];
    const int*   ei = (const int*)d_in[1];
    const float* W0 = (const float*)d_in[2];
    const float* b0 = (const float*)d_in[3];
    const float* W1 = (const float*)d_in[4];
    const float* b1 = (const float*)d_in[5];
    const float* Wv = (const float*)d_in[6];
    const float* bv = (const float*)d_in[7];
    const float* Wt = (const float*)d_in[8];
    const float* bt = (const float*)d_in[9];

    const int N = in_sizes[0] / DFEAT;
    const int E = in_sizes[1] / 2;
    const int* src = ei;
    const int* dst = ei + E;
    const int nbuk = (N + 255) >> BSH;

    // workspace carve-up
    char* w = (char*)d_ws;
    int* bucket_cnt = (int*)w;  w += align_up((size_t)(nbuk + 1) * 4, 256);
    int* bucket_off = (int*)w;  w += align_up((size_t)(nbuk + 1) * 4, 256);
    int* bucket_cur = (int*)w;  w += align_up((size_t)nbuk * 4, 256);
    unsigned* pk_arr = (unsigned*)w; w += align_up((size_t)E * 4, 256);
    int* row_ptr    = (int*)w;  w += align_up((size_t)(N + 1) * 4, 256);
    unsigned short* col_idx = (unsigned short*)w; w += align_up((size_t)E * 2, 256);
    float* dinv     = (float*)w; w += align_up((size_t)N * 4, 256);
    short* whi_all  = (short*)w; w += align_up(4 * 16384 * 2, 256);
    short* wlo_all  = (short*)w; w += align_up(4 * 16384 * 2, 256);
    __half* hs      = (__half*)w; w += align_up((size_t)N * DFEAT * 2, 256);
    __half* h1      = (__half*)w; w += align_up((size_t)N * DFEAT * 2, 256);

    short* w0hi = whi_all;            short* w0lo = wlo_all;
    short* w1hi = whi_all + 16384;    short* w1lo = wlo_all + 16384;
    short* wvhi = whi_all + 2*16384;  short* wvlo = wlo_all + 2*16384;
    short* wthi = whi_all + 3*16384;  short* wtlo = wlo_all + 3*16384;

    float* out_h = (float*)d_out;
    float* out_v = out_h + (size_t)N * DFEAT;
    float* out_t = out_h + 2 * (size_t)N * DFEAT;

    const int gb = (N + 127) / 128;
    const int agg_blocks = 2048;
    const int pb = (E + BKE - 1) / BKE;   // partition blocks (196)

    // CSR build (counting sort) + weight pre-split
    hipMemsetAsync(bucket_cnt, 0, (size_t)(nbuk + 1) * 4, stream);
    bucket_hist_k<<<256, 256, 0, stream>>>(dst, bucket_cnt, E, nbuk);
    prep_w4_k<<<256, 256, 0, stream>>>(W0, W1, Wv, Wt, whi_all, wlo_all);
    scan_buckets_k<<<1, 256, 0, stream>>>(bucket_cnt, bucket_off, bucket_cur, nbuk, E);
    partition_k<<<pb, 256, 0, stream>>>(src, dst, bucket_cur, pk_arr, E, nbuk);
    build_csr_k<<<nbuk, 256, 0, stream>>>(pk_arr, bucket_off, row_ptr, col_idx, dinv, N, E);

    // layer 0: hs = fp16( dinv * (x @ W0) )
    gemm_k<float, __half, true, false, false><<<gb, 256, 0, stream>>>(x, w0hi, w0lo, dinv, nullptr, hs, N);
    // h1 = fp16( relu(dinv * agg(hs) + b0) )
    agg_k<true, __half><<<agg_blocks, 256, 0, stream>>>(hs, row_ptr, col_idx, dinv, b0, h1, N);
    // layer 1: hs = fp16( dinv * (h1 @ W1) )
    gemm_k<__half, __half, true, false, false><<<gb, 256, 0, stream>>>(h1, w1hi, w1lo, dinv, nullptr, hs, N);
    // h = dinv * agg(hs) + b1 -> d_out (fp32)
    agg_k<false, float><<<agg_blocks, 256, 0, stream>>>(hs, row_ptr, col_idx, dinv, b1, out_h, N);
    // heads (fused dispatch)
    gemm_heads_k<<<2 * gb, 256, 0, stream>>>(out_h, wvhi, wvlo, wthi, wtlo, bv, bt, out_v, out_t, N, gb);
}